// Round 9
// baseline (643.079 us; speedup 1.0000x reference)
//
#include <hip/hip_runtime.h>

typedef _Float16 f16x8 __attribute__((ext_vector_type(8)));
typedef float f32x4 __attribute__((ext_vector_type(4)));

#define Dd 256
#define Hh 1024

// ---------- prep: pack weights fragment-major (validated round 7) ----------
// W1P tile (w,nt,kk) = ((w*8+nt)*8+kk): lane(q*16+ln)*8+j holds
//   W1[kk*32+q*8+j][w*128+nt*16+ln]  (B-fragment for 16x16x32 MFMA)
__global__ void pack_w1_kernel(const float* __restrict__ W1, _Float16* __restrict__ W1P) {
    int gid = blockIdx.x * 256 + threadIdx.x;       // 256*1024 elements
    int h = gid & 1023, d = gid >> 10;
    int w = h >> 7, nt = (h >> 4) & 7, ln = h & 15;
    int kk = d >> 5, q = (d >> 3) & 3, j = d & 7;
    W1P[(((w * 8 + nt) * 8 + kk) * 64 + q * 16 + ln) * 8 + j] = (_Float16)W1[d * 1024 + h];
}
// W2P tile (w,kk,t) = ((w*32+kk)*2+t)
__global__ void pack_w2_kernel(const float* __restrict__ W2, _Float16* __restrict__ W2P) {
    int gid = blockIdx.x * 256 + threadIdx.x;       // 1024*256 elements
    int dcol = gid & 255, h = gid >> 8;
    int w = dcol >> 5, t = (dcol >> 4) & 1, ln = dcol & 15;
    int kk = h >> 5, q = (h >> 3) & 3, j = h & 7;
    W2P[(((w * 32 + kk) * 2 + t) * 64 + q * 16 + ln) * 8 + j] = (_Float16)W2[h * 256 + dcol];
}

// raw 16B global load via 64-bit vaddr (round-8 saddr form failed: base is
// per-wave, not provably wave-uniform -> "s" constraint miscompiled).
// Opaque to compiler waitcnt tracking: correctness is OUR vmcnt discipline.
__device__ __forceinline__ void gload(f16x8& dst, const _Float16* addr) {
    asm volatile("global_load_dwordx4 %0, %1, off"
                 : "=v"(dst) : "v"(addr) : "memory");
}
// gate: oldest of the 16 outstanding loads has retired; ties v so the
// consuming MFMA is data-dependent on this asm (cannot be hoisted above).
__device__ __forceinline__ void wait15(f16x8& v) {
    asm volatile("s_waitcnt vmcnt(15)" : "+v"(v) :: "memory");
}
// LDS-only barrier: drains DS ops (act/z handoff) but leaves the 16 weight
// loads in flight — __syncthreads() would emit vmcnt(0) and drain the ring.
__device__ __forceinline__ void barrier_lgkm() {
    asm volatile("s_waitcnt lgkmcnt(0)\n\ts_barrier" ::: "memory");
}

// ---------------- main: 64 blocks x 512 thr, register weight ring ----------------
// Block owns 16 batch rows, whole solve, zero inter-block sync. Wave w owns
// H-slice [w*128,+128) (GEMM1: tiles 0..63) and D-slice [w*32,+32) (GEMM2:
// tiles 64..127). Perpetual modular stream: consume tile i, issue (i+16)%128
// into the same 16-slot VGPR ring; in-flight 16 KB/wave forever, across
// barriers and eval boundaries (weights constant). Weights never touch LDS.
__global__ __launch_bounds__(512, 2) void ode_kernel(
    const float* __restrict__ z0, const float* __restrict__ tv,
    const float* __restrict__ b1, const float* __restrict__ b2,
    const _Float16* __restrict__ W1P, const _Float16* __restrict__ W2P,
    float* __restrict__ out) {
    __shared__ _Float16 act_lds[16][1032];   // 33 KB (+8 pad: <=2-way banks, free)
    __shared__ _Float16 z_lds[16][264];      // 8.25 KB

    const int tid  = threadIdx.x;
    const int w    = tid >> 6;
    const int lane = tid & 63;
    const int ln   = lane & 15;
    const int q    = lane >> 4;
    const int m0   = blockIdx.x * 16;

    const float h = (tv[1] - tv[0]) * 0.125f;

    float bb1[8];
#pragma unroll
    for (int nt = 0; nt < 8; ++nt) bb1[nt] = b1[w * 128 + nt * 16 + ln];
    float bb2v[2];
#pragma unroll
    for (int t = 0; t < 2; ++t) bb2v[t] = b2[w * 32 + t * 16 + ln];

    // per-lane stream bases: wave-slice origin + this lane's 16B within a tile
    const _Float16* W1l = W1P + (size_t)(w * 64) * 512 + lane * 8;  // tiles 0..63
    const _Float16* W2l = W2P + (size_t)(w * 64) * 512 + lane * 8;  // tiles 64..127

    f16x8 buf[16];   // landing ring: 128 VGPRs

#define ISSUE_TILE(slot, ti) do {                                               \
        const _Float16* _p = ((ti) < 64) ? (W1l + (size_t)(ti) * 512)           \
                                         : (W2l + (size_t)((ti) - 64) * 512);   \
        gload(buf[slot], _p);                                                   \
    } while (0)

    // RK4 state in registers (C-layout): z[t][r] = z[m0+q*4+r][w*32+t*16+ln]
    f32x4 z[2], zsum[2];
#pragma unroll
    for (int t = 0; t < 2; ++t)
#pragma unroll
        for (int r = 0; r < 4; ++r)
            z[t][r] = z0[(m0 + q * 4 + r) * Dd + w * 32 + t * 16 + ln];
#pragma unroll
    for (int t = 0; t < 2; ++t)
#pragma unroll
        for (int r = 0; r < 4; ++r)
            z_lds[q * 4 + r][w * 32 + t * 16 + ln] = (_Float16)z[t][r];
    __syncthreads();   // full barrier OK here: ring not yet primed

    // prime the perpetual ring: tiles 0..15
#pragma unroll
    for (int p = 0; p < 16; ++p) ISSUE_TILE(p, p);

#pragma unroll 1
    for (int ev = 0; ev < 32; ++ev) {
        const int e = ev & 3;

        // ---- GEMM1: act[:, w*128..+128) = tanh(z @ W1 + b1), tiles i=0..63 ----
        f16x8 a1[8];
#pragma unroll
        for (int kk = 0; kk < 8; ++kk)
            a1[kk] = *(const f16x8*)&z_lds[ln][kk * 32 + q * 8];

#pragma unroll
        for (int nt = 0; nt < 8; ++nt) {
            f32x4 acc = {0.f, 0.f, 0.f, 0.f};
#pragma unroll
            for (int kk = 0; kk < 8; ++kk) {
                const int i = nt * 8 + kk, s = i & 15;
                wait15(buf[s]);
                acc = __builtin_amdgcn_mfma_f32_16x16x32_f16(a1[kk], buf[s], acc, 0, 0, 0);
                ISSUE_TILE(s, (i + 16) & 127);
            }
#pragma unroll
            for (int r = 0; r < 4; ++r) {
                float x = acc[r] + bb1[nt];
                float ex = __expf(2.0f * x);
                act_lds[q * 4 + r][w * 128 + nt * 16 + ln] =
                    (_Float16)(1.0f - 2.0f / (ex + 1.0f));
            }
        }
        barrier_lgkm();   // act visible; weight ring stays in flight

        // ---- GEMM2: k[:, w*32..+32) = act @ W2 + b2, tiles i=64..127 ----
        f32x4 acc2[2] = {{0.f, 0.f, 0.f, 0.f}, {0.f, 0.f, 0.f, 0.f}};
        f16x8 a2r[4];   // 2-ahead a2 prefetch ring (ds_read latency cover)
        a2r[0] = *(const f16x8*)&act_lds[ln][0 * 32 + q * 8];
        a2r[1] = *(const f16x8*)&act_lds[ln][1 * 32 + q * 8];
#pragma unroll
        for (int kk = 0; kk < 32; ++kk) {
            if (kk + 2 < 32)
                a2r[(kk + 2) & 3] = *(const f16x8*)&act_lds[ln][(kk + 2) * 32 + q * 8];
#pragma unroll
            for (int t = 0; t < 2; ++t) {
                const int i = 64 + kk * 2 + t, s = i & 15;
                wait15(buf[s]);
                acc2[t] = __builtin_amdgcn_mfma_f32_16x16x32_f16(a2r[kk & 3], buf[s], acc2[t], 0, 0, 0);
                ISSUE_TILE(s, (i + 16) & 127);   // i>=112 prefetches next eval's tiles 0..15
            }
        }

        // ---- RK4 epilogue (registers) ----
#pragma unroll
        for (int t = 0; t < 2; ++t) {
            f32x4 kv, za;
#pragma unroll
            for (int r = 0; r < 4; ++r) kv[r] = acc2[t][r] + bb2v[t];
            if (e == 0) {
                zsum[t] = kv;
            } else if (e == 3) {
#pragma unroll
                for (int r = 0; r < 4; ++r) zsum[t][r] += kv[r];
            } else {
#pragma unroll
                for (int r = 0; r < 4; ++r) zsum[t][r] += 2.0f * kv[r];
            }
            if (e < 3) {
                const float c = (e == 2) ? h : 0.5f * h;
#pragma unroll
                for (int r = 0; r < 4; ++r) za[r] = z[t][r] + c * kv[r];
            } else {
#pragma unroll
                for (int r = 0; r < 4; ++r) {
                    z[t][r] += (h * (1.0f / 6.0f)) * zsum[t][r];
                    za[r] = z[t][r];
                }
            }
#pragma unroll
            for (int r = 0; r < 4; ++r)
                z_lds[q * 4 + r][w * 32 + t * 16 + ln] = (_Float16)za[r];
        }
        barrier_lgkm();   // z visible; ring still in flight into next eval
    }

    // drain the ring before endpgm (outstanding loads must not outlive the wave)
    asm volatile("s_waitcnt vmcnt(0)" ::: "memory");

#pragma unroll
    for (int t = 0; t < 2; ++t)
#pragma unroll
        for (int r = 0; r < 4; ++r)
            out[(m0 + q * 4 + r) * Dd + w * 32 + t * 16 + ln] = z[t][r];
#undef ISSUE_TILE
}

extern "C" void kernel_launch(void* const* d_in, const int* in_sizes, int n_in,
                              void* d_out, int out_size, void* d_ws, size_t ws_size,
                              hipStream_t stream) {
    const float* z0 = (const float*)d_in[0];
    const float* tv = (const float*)d_in[1];
    const float* W1 = (const float*)d_in[2];   // [256][1024]
    const float* b1 = (const float*)d_in[3];   // [1024]
    const float* W2 = (const float*)d_in[4];   // [1024][256]
    const float* b2 = (const float*)d_in[5];   // [256]
    float* out = (float*)d_out;

    _Float16* W1P = (_Float16*)d_ws;           // 512 KB fragment-major
    _Float16* W2P = W1P + Hh * Dd;             // 512 KB fragment-major

    pack_w1_kernel<<<1024, 256, 0, stream>>>(W1, W1P);
    pack_w2_kernel<<<1024, 256, 0, stream>>>(W2, W2P);

    ode_kernel<<<64, 512, 0, stream>>>(z0, tv, b1, b2, W1P, W2P, out);
}